// Round 9
// baseline (121.379 us; speedup 1.0000x reference)
//
#include <hip/hip_runtime.h>
#include <math.h>

#define BSZ   16
#define LSEQ  1024
#define TGT   256
#define HID   512
#define TV    2000
#define VOC   3000
#define SRC   2048
#define NKE   1280     // WkE rows: 2 j-halves x 640 (512 d + sentinel + bias + pad)
#define JOFF  640
#define SCALE 0.044194173824159216f   // 1/sqrt(512)

typedef unsigned short u16;
typedef __attribute__((ext_vector_type(8))) short bf16x8;
typedef __attribute__((ext_vector_type(4))) float f32x4;

__device__ __forceinline__ u16 f2bf(float x) {
    unsigned u = __float_as_uint(x);
    u += 0x7FFFu + ((u >> 16) & 1u);
    return (u16)(u >> 16);
}
__device__ __forceinline__ float bf2f(u16 x) {
    return __uint_as_float((unsigned)x << 16);
}

static __device__ __forceinline__ float gelu_exact(float x) {
    return 0.5f * x * (1.0f + erff(x * 0.70710678118654752f));
}

// async 16B global -> LDS (wave-uniform LDS base + lane*16)
__device__ __forceinline__ void gload16(const u16* g, u16* l) {
    __builtin_amdgcn_global_load_lds(
        (const __attribute__((address_space(1))) unsigned int*)g,
        (__attribute__((address_space(3))) unsigned int*)l,
        16, 0, 0);
}

// ---------------- PREP mega-kernel ----------------
// blocks: [0,4096) cast memory_raw | [4096,5120) cast feature | [5120,5376) Wq^T |
//         [5376,5696) WkE build | [5696,6720) k_logz | [6720,6736) ce_perm | 6736 rowsum=0
__device__ __forceinline__ void cast8_body(const float4* __restrict__ in,
                                           int4* __restrict__ out, int i) {
    float4 x = in[2 * i], y = in[2 * i + 1];
    unsigned p0 = (unsigned)f2bf(x.x) | ((unsigned)f2bf(x.y) << 16);
    unsigned p1 = (unsigned)f2bf(x.z) | ((unsigned)f2bf(x.w) << 16);
    unsigned p2 = (unsigned)f2bf(y.x) | ((unsigned)f2bf(y.y) << 16);
    unsigned p3 = (unsigned)f2bf(y.z) | ((unsigned)f2bf(y.w) << 16);
    out[i] = make_int4(p0, p1, p2, p3);
}

__global__ __launch_bounds__(256) void prep(
    const float* __restrict__ memory_raw, const float* __restrict__ feature,
    const float* __restrict__ Wq, const float* __restrict__ Wk,
    const float* __restrict__ sentinel, const float* __restrict__ bk,
    const float* __restrict__ logits, const int* __restrict__ ce,
    int4* __restrict__ memb, int4* __restrict__ featb,
    u16* __restrict__ wqT, u16* __restrict__ wkE,
    float* __restrict__ logZo, int* __restrict__ ce_perm,
    float* __restrict__ rowsum)
{
    __shared__ float t[32][33];
    const int id = blockIdx.x;
    const int tid = threadIdx.x;
    if (id < 4096) {
        cast8_body((const float4*)memory_raw, memb, id * 256 + tid);
    } else if (id < 5120) {
        cast8_body((const float4*)feature, featb, (id - 4096) * 256 + tid);
    } else if (id < 5376) {
        // Wq^T (512x512)
        int id2 = id - 5120;
        int bx = (id2 & 15) * 32, by = (id2 >> 4) * 32;
        const int tx = tid & 31, ty = tid >> 5;
        #pragma unroll
        for (int k = 0; k < 4; ++k)
            t[ty + 8 * k][tx] = Wq[(size_t)(by + ty + 8 * k) * 512 + bx + tx];
        __syncthreads();
        #pragma unroll
        for (int k = 0; k < 4; ++k)
            wqT[(size_t)(bx + ty + 8 * k) * 512 + by + tx] = f2bf(t[tx][ty + 8 * k]);
    } else if (id < 5696) {
        // WkE build: 4 rows per block, 64 threads x 8 cols per row
        const int rr = (id - 5376) * 4 + (tid >> 6);   // 0..1279
        const int c = (tid & 63) * 8;
        const int j = rr >= JOFF;
        const int dd = rr - j * JOFF;
        u16* dst = wkE + (size_t)rr * HID + c;
        if (dd < 512) {
            const float* src = Wk + (size_t)dd * 1024 + j * 512 + c;
            #pragma unroll
            for (int k = 0; k < 8; ++k) dst[k] = f2bf(src[k]);
        } else if (dd == 512) {
            #pragma unroll
            for (int k = 0; k < 8; ++k) dst[k] = f2bf(sentinel[c + k]);
        } else if (dd == 513) {
            #pragma unroll
            for (int k = 0; k < 8; ++k) dst[k] = f2bf(bk[j * 512 + c + k]);
        } else {
            #pragma unroll
            for (int k = 0; k < 8; ++k) dst[k] = 0;
        }
    } else if (id < 6720) {
        // k_logz: 4 rows per block, one wave per row (TV = 500 float4)
        const int row = (id - 5696) * 4 + (tid >> 6);
        const int lane = tid & 63;
        const float4* lrow4 = (const float4*)(logits + (size_t)row * TV);
        float4 v4[8];
        float m = -INFINITY;
        #pragma unroll
        for (int i = 0; i < 8; ++i) {
            int idx = lane + 64 * i;
            if (idx < 500) {
                v4[i] = lrow4[idx];
                m = fmaxf(m, fmaxf(fmaxf(v4[i].x, v4[i].y), fmaxf(v4[i].z, v4[i].w)));
            } else {
                v4[i] = make_float4(-INFINITY, -INFINITY, -INFINITY, -INFINITY);
            }
        }
        #pragma unroll
        for (int o = 32; o > 0; o >>= 1) m = fmaxf(m, __shfl_xor(m, o, 64));
        float s = 0.f;
        #pragma unroll
        for (int i = 0; i < 8; ++i) {
            s += __expf(v4[i].x - m) + __expf(v4[i].y - m)
               + __expf(v4[i].z - m) + __expf(v4[i].w - m);
        }
        #pragma unroll
        for (int o = 32; o > 0; o >>= 1) s += __shfl_xor(s, o, 64);
        if (lane == 0) logZo[row] = m + __logf(s);
    } else if (id < 6736) {
        // ce_perm: ce_perm[b][j*1024+l] = ce[b][2l+j]
        const int b = id - 6720;
        const int* ceb = ce + (size_t)b * SRC;
        int* cpb = ce_perm + (size_t)b * SRC;
        for (int jl = tid; jl < SRC; jl += 256) {
            int j = jl >> 10, l = jl & 1023;
            cpb[jl] = ceb[2 * l + j];
        }
    } else {
        // zero rowsum (4096 f32 = 1024 float4) — fresh every launch
        float4* rz = (float4*)rowsum;
        for (int i = tid; i < 1024; i += 256) rz[i] = make_float4(0.f, 0.f, 0.f, 0.f);
    }
}

// ---------------- MFMA GEMM body: C = A[M,512] . B^T[N,512], 128x128 tile ----------------
// EPI 1: query (+bq, gelu) -> bf16 [m][512]
// EPI 3: qk (plain)        -> bf16 [m][1280]
// EPI 2: atten (bias + scale + EXP + mask + row-partial-sum) -> bf16 e-values, z=(b,jj)
template<int EPI, int LDA>
__device__ __forceinline__ void gemm_body(
    int m0, int n0, int z,
    const u16* __restrict__ Abase, const u16* __restrict__ Bbase,
    const float* __restrict__ bias, u16* __restrict__ outb,
    const int* __restrict__ ce_perm, float* __restrict__ rowsum,
    u16* __restrict__ As, u16* __restrict__ Bs)   // each 2*4096 u16
{
    const int tid = threadIdx.x;
    const int lane = tid & 63;
    const int w = tid >> 6;
    const int wr = (w >> 1) * 64, wc = (w & 1) * 64;

    const u16* Ag = Abase;
    const u16* Bg = Bbase;
    if (EPI == 2) {
        Ag = Abase + (size_t)(z >> 1) * TGT * NKE + (size_t)(z & 1) * JOFF;
        Bg = Bbase + (size_t)(z >> 1) * LSEQ * HID;
    }

    const int chunkrow = lane >> 2;
    const int colc = (lane & 3) * 8;
    const int c0 = w * 2, c1 = c0 + 1;
    const u16* gA0 = Ag + (size_t)(m0 + c0 * 16 + chunkrow) * LDA + colc;
    const u16* gA1 = Ag + (size_t)(m0 + c1 * 16 + chunkrow) * LDA + colc;
    const u16* gB0 = Bg + (size_t)(n0 + c0 * 16 + chunkrow) * HID + colc;
    const u16* gB1 = Bg + (size_t)(n0 + c1 * 16 + chunkrow) * HID + colc;

    const int la = lane & 15, lb = lane >> 4;
    f32x4 acc[4][4] = {};

    gload16(gA0, As + c0 * 512);
    gload16(gA1, As + c1 * 512);
    gload16(gB0, Bs + c0 * 512);
    gload16(gB1, Bs + c1 * 512);

    int cur = 0;
    for (int k0 = 0; k0 < HID; k0 += 32) {
        __syncthreads();   // drains vmcnt(0) (stage complete) + barrier
        const u16* Asb = As + cur * 4096;
        const u16* Bsb = Bs + cur * 4096;
        bf16x8 af[4], bfv[4];
        #pragma unroll
        for (int i = 0; i < 4; ++i)
            af[i] = *(const bf16x8*)(Asb + (wr + i * 16 + la) * 32 + lb * 8);
        #pragma unroll
        for (int j = 0; j < 4; ++j)
            bfv[j] = *(const bf16x8*)(Bsb + (wc + j * 16 + la) * 32 + lb * 8);
        if (k0 + 32 < HID) {
            const int nb = cur ^ 1;
            u16* An = As + nb * 4096;
            u16* Bn = Bs + nb * 4096;
            gload16(gA0 + k0 + 32, An + c0 * 512);
            gload16(gA1 + k0 + 32, An + c1 * 512);
            gload16(gB0 + k0 + 32, Bn + c0 * 512);
            gload16(gB1 + k0 + 32, Bn + c1 * 512);
        }
        #pragma unroll
        for (int i = 0; i < 4; ++i)
            #pragma unroll
            for (int j = 0; j < 4; ++j)
                acc[i][j] = __builtin_amdgcn_mfma_f32_16x16x32_bf16(af[i], bfv[j], acc[i][j], 0, 0, 0);
        cur ^= 1;
    }

    const int r_l = (lane >> 4) * 4, c_l = lane & 15;
    if (EPI == 1) {
        #pragma unroll
        for (int j = 0; j < 4; ++j) {
            const int n = n0 + wc + j * 16 + c_l;
            const float bv = bias[n];
            #pragma unroll
            for (int i = 0; i < 4; ++i)
                #pragma unroll
                for (int r = 0; r < 4; ++r) {
                    const int m = m0 + wr + i * 16 + r_l + r;
                    outb[(size_t)m * HID + n] = f2bf(gelu_exact(acc[i][j][r] + bv));
                }
        }
    } else if (EPI == 3) {
        #pragma unroll
        for (int j = 0; j < 4; ++j) {
            const int n = n0 + wc + j * 16 + c_l;
            #pragma unroll
            for (int i = 0; i < 4; ++i)
                #pragma unroll
                for (int r = 0; r < 4; ++r) {
                    const int m = m0 + wr + i * 16 + r_l + r;
                    outb[(size_t)m * NKE + n] = f2bf(acc[i][j][r]);
                }
        }
    } else {
        const int b = z >> 1, jj = z & 1;
        // per-row bias (q.bk_j) gathered from qk row; per-col mask from ce_perm
        float biasr[4][4];
        #pragma unroll
        for (int i = 0; i < 4; ++i)
            #pragma unroll
            for (int r = 0; r < 4; ++r) {
                const int tt = m0 + wr + i * 16 + r_l + r;
                biasr[i][r] = bf2f(Abase[(size_t)(b * TGT + tt) * NKE + jj * JOFF + 513]);
            }
        int cj[4];
        #pragma unroll
        for (int j = 0; j < 4; ++j)
            cj[j] = ce_perm[(size_t)b * SRC + jj * 1024 + n0 + wc + j * 16 + c_l];
        #pragma unroll
        for (int i = 0; i < 4; ++i)
            #pragma unroll
            for (int r = 0; r < 4; ++r) {
                const int tt = m0 + wr + i * 16 + r_l + r;
                float rs = 0.f;
                #pragma unroll
                for (int j = 0; j < 4; ++j) {
                    const int l = n0 + wc + j * 16 + c_l;
                    float ev = (cj[j] == 0) ? 0.f
                             : __expf((acc[i][j][r] + biasr[i][r]) * SCALE);
                    outb[(size_t)(b * TGT + tt) * SRC + jj * 1024 + l] = f2bf(ev);
                    rs += ev;
                }
                rs += __shfl_xor(rs, 1, 64);
                rs += __shfl_xor(rs, 2, 64);
                rs += __shfl_xor(rs, 4, 64);
                rs += __shfl_xor(rs, 8, 64);
                if (c_l == 0) atomicAdd(&rowsum[b * TGT + tt], rs);
            }
    }
}

__global__ __launch_bounds__(256) void gemm_query(
    const u16* __restrict__ feat, const u16* __restrict__ wqT,
    const float* __restrict__ bq, u16* __restrict__ queryb)
{
    __shared__ u16 As[2 * 4096];
    __shared__ u16 Bs[2 * 4096];
    gemm_body<1, 512>(blockIdx.y * 128, blockIdx.x * 128, 0,
                      feat, wqT, bq, queryb, nullptr, nullptr, As, Bs);
}

__global__ __launch_bounds__(256) void gemm_qk(
    const u16* __restrict__ queryb, const u16* __restrict__ wkE,
    u16* __restrict__ qkb)
{
    __shared__ u16 As[2 * 4096];
    __shared__ u16 Bs[2 * 4096];
    gemm_body<3, 512>(blockIdx.y * 128, blockIdx.x * 128, 0,
                      queryb, wkE, nullptr, qkb, nullptr, nullptr, As, Bs);
}

__global__ __launch_bounds__(256) void gemm_atten(
    const u16* __restrict__ qkb, const u16* __restrict__ memb,
    const int* __restrict__ ce_perm, float* __restrict__ rowsum,
    u16* __restrict__ atten_e)
{
    __shared__ u16 As[2 * 4096];
    __shared__ u16 Bs[2 * 4096];
    gemm_body<2, NKE>(blockIdx.y * 128, blockIdx.x * 128, blockIdx.z,
                      qkb, memb, nullptr, atten_e, ce_perm, rowsum, As, Bs);
}

// ---------------- finalize: wave-owned rows, barrier-free ----------------
// 4 rows per block; wave w owns row blockIdx.x*4+w with private p[w][3000].
__global__ __launch_bounds__(256) void finalize(
    const u16* __restrict__ atten_e, const int* __restrict__ ce_perm,
    const u16* __restrict__ qkb, const float* __restrict__ rowsum,
    const float* __restrict__ out_logits, const float* __restrict__ logZo,
    float* __restrict__ out)
{
    __shared__ float p[4][VOC];
    const int w = threadIdx.x >> 6;
    const int lane = threadIdx.x & 63;
    const int bt = blockIdx.x * 4 + w;
    const int b = bt >> 8;
    const float EPSF = 1.1920929e-07f;

    float* pw = p[w];
    float4* p4 = (float4*)pw;
    #pragma unroll
    for (int k = 0; k < 12; ++k) {
        int i = lane + 64 * k;
        if (i < 750) p4[i] = make_float4(0.f, 0.f, 0.f, 0.f);
    }

    // row stats (all lanes redundantly, no reductions)
    const float sent_v = bf2f(qkb[(size_t)bt * NKE + 512]) * SCALE;
    const float se = __expf(sent_v);
    const float sm = rowsum[bt] + se;
    const float inv = 1.0f / sm;
    const float g = sent_v - __logf(sm);   // log gate
    const float eg = se * inv;
    const float dl = __logf(1.0f - eg + EPSF) - log1pf(-eg + EPSF);  // ~0 (rounding)
    const float edl = __expf(dl);
    const float gZ = g - logZo[bt];

    // scatter: 2048 e-values for this row (32 per lane), intra-wave only
    const int4* evp = (const int4*)(atten_e + (size_t)bt * SRC);
    const int4* cep = (const int4*)(ce_perm + (size_t)b * SRC);
    #pragma unroll
    for (int kk = 0; kk < 4; ++kk) {
        const int idx = lane + 64 * kk;
        int4 ev4 = evp[idx];
        int4 c40 = cep[2 * idx];
        int4 c41 = cep[2 * idx + 1];
        atomicAdd(&pw[c40.x], bf2f((u16)(ev4.x & 0xffff)) * inv);
        atomicAdd(&pw[c40.y], bf2f((u16)((unsigned)ev4.x >> 16)) * inv);
        atomicAdd(&pw[c40.z], bf2f((u16)(ev4.y & 0xffff)) * inv);
        atomicAdd(&pw[c40.w], bf2f((u16)((unsigned)ev4.y >> 16)) * inv);
        atomicAdd(&pw[c41.x], bf2f((u16)(ev4.z & 0xffff)) * inv);
        atomicAdd(&pw[c41.y], bf2f((u16)((unsigned)ev4.z >> 16)) * inv);
        atomicAdd(&pw[c41.z], bf2f((u16)(ev4.w & 0xffff)) * inv);
        atomicAdd(&pw[c41.w], bf2f((u16)((unsigned)ev4.w >> 16)) * inv);
    }
    // wave-local: all 64 lanes' atomics issued in lockstep above; drain LDS pipe
    __asm__ volatile("s_waitcnt lgkmcnt(0)" ::: "memory");

    const float4* lrow4 = (const float4*)(out_logits + (size_t)bt * TV);
    float4* orow4 = (float4*)(out + (size_t)bt * VOC);
    #pragma unroll
    for (int k = 0; k < 12; ++k) {
        int idx = lane + 64 * k;
        if (idx >= 750) continue;
        float4 pv = p4[idx];
        float4 o;
        if (idx < 500) {
            float4 lv = lrow4[idx];
            o.x = __logf(__expf(lv.x + gZ) + (pv.x + EPSF) * edl);
            o.y = __logf(__expf(lv.y + gZ) + (pv.y + EPSF) * edl);
            o.z = __logf(__expf(lv.z + gZ) + (pv.z + EPSF) * edl);
            o.w = __logf(__expf(lv.w + gZ) + (pv.w + EPSF) * edl);
        } else {
            o.x = __logf(pv.x + EPSF) + dl;
            o.y = __logf(pv.y + EPSF) + dl;
            o.z = __logf(pv.z + EPSF) + dl;
            o.w = __logf(pv.w + EPSF) + dl;
        }
        orow4[idx] = o;
    }
}

extern "C" void kernel_launch(void* const* d_in, const int* in_sizes, int n_in,
                              void* d_out, int out_size, void* d_ws, size_t ws_size,
                              hipStream_t stream) {
    const float* out_logits = (const float*)d_in[0];
    const float* feature    = (const float*)d_in[1];
    const float* memory_raw = (const float*)d_in[2];
    const int*   content_e  = (const int*)d_in[3];
    const float* Wq = (const float*)d_in[4];
    const float* bq = (const float*)d_in[5];
    const float* Wk = (const float*)d_in[6];
    const float* bk = (const float*)d_in[7];
    const float* sentinel = (const float*)d_in[8];
    float* out = (float*)d_out;

    u16* memb   = (u16*)d_ws;                             // 16384*512 bf16
    u16* featb  = memb   + (size_t)16384 * 512;           // 4096*512
    u16* wqT    = featb  + (size_t)4096 * 512;            // 512*512
    u16* wkE    = wqT    + (size_t)512 * 512;             // 1280*512
    u16* queryb = wkE    + (size_t)NKE * 512;             // 4096*512
    u16* qkb    = queryb + (size_t)4096 * 512;            // 4096*1280
    u16* atten_eb = qkb  + (size_t)4096 * NKE;            // 4096*2048 bf16 e-values
    float* logZo = (float*)(atten_eb + (size_t)4096 * SRC); // 4096 f32
    int* ce_perm = (int*)(logZo + 4096);                  // 16*2048 int
    float* rowsum = (float*)(ce_perm + (size_t)BSZ * SRC); // 4096 f32

    prep<<<6737, 256, 0, stream>>>(memory_raw, feature, Wq, Wk, sentinel, bk,
                                   out_logits, content_e,
                                   (int4*)memb, (int4*)featb, wqT, wkE, logZo,
                                   ce_perm, rowsum);
    gemm_query<<<dim3(4, 32), 256, 0, stream>>>(featb, wqT, bq, queryb);
    gemm_qk<<<dim3(10, 32), 256, 0, stream>>>(queryb, wkE, qkb);
    gemm_atten<<<dim3(8, 2, 32), 256, 0, stream>>>(qkb, memb, ce_perm, rowsum, atten_eb);
    finalize<<<1024, 256, 0, stream>>>(atten_eb, ce_perm, qkb, rowsum,
                                       out_logits, logZo, out);
}